// Round 3
// baseline (490.255 us; speedup 1.0000x reference)
//
#include <hip/hip_runtime.h>
#include <hip/hip_bf16.h>
#include <math.h>

// Problem constants
#define BB 4
#define CC 256
#define NN 4096          // H*W
#define EE 96
#define NTOT (BB*NN)     // 16384 rows

typedef __attribute__((ext_vector_type(8))) short bf16x8;
typedef __attribute__((ext_vector_type(4))) float f32x4;

__device__ __forceinline__ short f2bf(float x) {
    __hip_bfloat16 h = __float2bfloat16(x);
    return *reinterpret_cast<short*>(&h);
}
__device__ __forceinline__ float bf2f(short s) {
    unsigned int u = ((unsigned int)(unsigned short)s) << 16;
    float f;
    __builtin_memcpy(&f, &u, 4);
    return f;
}
__device__ __forceinline__ float gelu_exact(float v) {
    return 0.5f * v * (1.0f + erff(v * 0.70710678118654752f));
}

// Weight arena offsets (shorts). wg split into 256-stride matrix + last col.
#define OFF_WQ  0
#define OFF_WK  24576
#define OFF_WV  49152
#define OFF_WO  114688
#define OFF_WD1 180224
#define OFF_WD2 311296
#define OFF_WG  376832
#define OFF_WGL 442368
#define W16_TOTAL 442624

// ---------------------------------------------------------------------------
// Weight fp32 -> bf16 converter
// ---------------------------------------------------------------------------
__global__ void wconv_kernel(const float* __restrict__ wq, const float* __restrict__ wk,
                             const float* __restrict__ wv, const float* __restrict__ wo,
                             const float* __restrict__ wd1, const float* __restrict__ wd2,
                             const float* __restrict__ wg, short* __restrict__ W16) {
    int i = blockIdx.x * 256 + threadIdx.x;
    if (i >= W16_TOTAL) return;
    float v;
    if      (i < OFF_WK)  v = wq[i];
    else if (i < OFF_WV)  v = wk[i - OFF_WK];
    else if (i < OFF_WO)  v = wv[i - OFF_WV];
    else if (i < OFF_WD1) v = wo[i - OFF_WO];
    else if (i < OFF_WD2) v = wd1[i - OFF_WD1];
    else if (i < OFF_WG)  v = wd2[i - OFF_WD2];
    else if (i < OFF_WGL) { int l = i - OFF_WG; v = wg[(l >> 8) * 257 + (l & 255)]; }
    else                  v = wg[(i - OFF_WGL) * 257 + 256];
    W16[i] = f2bf(v);
}

// ---------------------------------------------------------------------------
// Kernel 1: channel LayerNorm + transpose, 32-position tiles (4 blocks/CU).
// Emits bf16 Xt16 (= x, row-major) and Xn16 (normed).
// ---------------------------------------------------------------------------
__global__ __launch_bounds__(256) void ln_kernel(
    const float* __restrict__ x, const float* __restrict__ gamma,
    const float* __restrict__ beta,
    short* __restrict__ Xt16, short* __restrict__ Xn16) {
    __shared__ float tile[256 * 33];
    __shared__ float psum[8][32], psq[8][32];
    __shared__ float mu_s[32], rs_s[32];
    __shared__ float gs[256], bs[256];
    const int b  = blockIdx.x >> 7;
    const int p0 = (blockIdx.x & 127) * 32;
    const int tid = threadIdx.x;
    const float* xb = x + (size_t)b * CC * NN;

    gs[tid] = gamma[tid];
    bs[tid] = beta[tid];
    #pragma unroll
    for (int i = 0; i < 8; ++i) {
        int idx = tid + i * 256;
        int c = idx >> 3, p4 = (idx & 7) * 4;
        float4 v = *(const float4*)&xb[(size_t)c * NN + p0 + p4];
        tile[c * 33 + p4]     = v.x;
        tile[c * 33 + p4 + 1] = v.y;
        tile[c * 33 + p4 + 2] = v.z;
        tile[c * 33 + p4 + 3] = v.w;
    }
    __syncthreads();
    {
        int col = tid & 31, part = tid >> 5;
        float s = 0.f, sq = 0.f;
        for (int r = part * 32; r < part * 32 + 32; ++r) {
            float v = tile[r * 33 + col];
            s += v; sq += v * v;
        }
        psum[part][col] = s; psq[part][col] = sq;
    }
    __syncthreads();
    if (tid < 32) {
        float S = 0.f, SQ = 0.f;
        #pragma unroll
        for (int j = 0; j < 8; ++j) { S += psum[j][tid]; SQ += psq[j][tid]; }
        float mu = S / 256.0f;
        float var = SQ / 256.0f - mu * mu;
        mu_s[tid] = mu;
        rs_s[tid] = rsqrtf(var + 1e-5f);
    }
    __syncthreads();
    size_t rowbase = ((size_t)b * NN + p0) * CC;
    #pragma unroll
    for (int i = 0; i < 4; ++i) {
        int idx = tid + i * 256;
        int p = idx >> 5, c8 = (idx & 31) * 8;
        float mu = mu_s[p], rcp = rs_s[p];
        bf16x8 xt, xn;
        #pragma unroll
        for (int j = 0; j < 8; ++j) {
            float v = tile[(c8 + j) * 33 + p];
            float n = (v - mu) * rcp * gs[c8 + j] + bs[c8 + j];
            xt[j] = f2bf(v); xn[j] = f2bf(n);
        }
        size_t o = rowbase + (size_t)p * CC + c8;
        *(bf16x8*)&Xt16[o] = xt;
        *(bf16x8*)&Xn16[o] = xn;
    }
}

// ---------------------------------------------------------------------------
// Kernel 2: LDS-free Q+K projection + cosine norm. 32 rows/block, grid 512.
// Waves 0,1: Q for row-halves; waves 2,3: K. A/B frags direct from global.
// ---------------------------------------------------------------------------
__global__ __launch_bounds__(256) void qkproj_kernel(
    const short* __restrict__ Xn16, const short* __restrict__ W16,
    const float* __restrict__ mask, const float* __restrict__ w_qm,
    short* __restrict__ Q16, short* __restrict__ K16)
{
    const int tid = threadIdx.x;
    const int w = tid >> 6, lane = tid & 63, ln = lane & 15, quad = lane >> 4;
    const int m0 = blockIdx.x * 32 + (w & 1) * 16;
    const bool isQ = (w < 2);
    const int woff = isQ ? OFF_WQ : OFF_WK;

    f32x4 acc[6];
    #pragma unroll
    for (int i = 0; i < 6; ++i) acc[i] = (f32x4){0.f, 0.f, 0.f, 0.f};

    #pragma unroll
    for (int kt = 0; kt < 8; ++kt) {
        bf16x8 af = *(const bf16x8*)&Xn16[(size_t)(m0 + ln) * 256 + kt * 32 + quad * 8];
        #pragma unroll
        for (int nt = 0; nt < 6; ++nt) {
            bf16x8 bf = *(const bf16x8*)&W16[woff + (size_t)(nt * 16 + ln) * 256 + kt * 32 + quad * 8];
            acc[nt] = __builtin_amdgcn_mfma_f32_16x16x32_bf16(af, bf, acc[nt], 0, 0, 0);
        }
    }

    short* outp = isQ ? Q16 : K16;
    #pragma unroll
    for (int r = 0; r < 4; ++r) {
        int row = m0 + quad * 4 + r;
        float mrow = isQ ? mask[row] : 0.f;
        float vals[6];
        float ss = 0.f;
        #pragma unroll
        for (int nt = 0; nt < 6; ++nt) {
            float v = acc[nt][r];
            if (isQ) v += mrow * w_qm[nt * 16 + ln];
            vals[nt] = v;
            ss += v * v;
        }
        ss += __shfl_xor(ss, 1, 64); ss += __shfl_xor(ss, 2, 64);
        ss += __shfl_xor(ss, 4, 64); ss += __shfl_xor(ss, 8, 64);
        float sc = 1.0f / fmaxf(sqrtf(ss), 1e-12f);
        #pragma unroll
        for (int nt = 0; nt < 6; ++nt)
            outp[(size_t)row * EE + nt * 16 + ln] = f2bf(vals[nt] * sc);
    }
}

// ---------------------------------------------------------------------------
// Kernel 3: LDS-free V projection, transposed store to V16t [B,C,N].
// 32 rows/block, grid 512. GEMM direct-global; only the transpose uses LDS.
// ---------------------------------------------------------------------------
__global__ __launch_bounds__(256) void vproj_kernel(
    const short* __restrict__ Xt16, const short* __restrict__ W16,
    short* __restrict__ V16t)
{
    __shared__ short Vt[256 * 40];
    const int tid = threadIdx.x;
    const int w = tid >> 6, lane = tid & 63, ln = lane & 15, quad = lane >> 4;
    const int m0 = blockIdx.x * 32;
    const int wm = w >> 1, wn = w & 1;
    const int mrow = m0 + wm * 16;

    f32x4 acc[8];
    #pragma unroll
    for (int i = 0; i < 8; ++i) acc[i] = (f32x4){0.f, 0.f, 0.f, 0.f};

    #pragma unroll
    for (int kt = 0; kt < 8; ++kt) {
        bf16x8 af = *(const bf16x8*)&Xt16[(size_t)(mrow + ln) * 256 + kt * 32 + quad * 8];
        #pragma unroll
        for (int nt = 0; nt < 8; ++nt) {
            int col = wn * 128 + nt * 16 + ln;
            bf16x8 bf = *(const bf16x8*)&W16[OFF_WV + (size_t)col * 256 + kt * 32 + quad * 8];
            acc[nt] = __builtin_amdgcn_mfma_f32_16x16x32_bf16(af, bf, acc[nt], 0, 0, 0);
        }
    }
    #pragma unroll
    for (int nt = 0; nt < 8; ++nt) {
        int ch = wn * 128 + nt * 16 + ln;
        #pragma unroll
        for (int r = 0; r < 4; ++r)
            Vt[ch * 40 + wm * 16 + quad * 4 + r] = f2bf(acc[nt][r]);
    }
    __syncthreads();
    const int b = m0 >> 12, p0l = m0 & 4095;
    #pragma unroll
    for (int i = 0; i < 4; ++i) {
        int idx = tid + i * 256;
        int ch = idx >> 2, p8 = (idx & 3) * 8;
        *(bf16x8*)&V16t[((size_t)b * CC + ch) * NN + p0l + p8] =
            *(const bf16x8*)&Vt[ch * 40 + p8];
    }
}

// ---------------------------------------------------------------------------
// Kernel 4: MFMA attention, 4-way K-split. v4: BARRIER-FREE loop.
// Post-mortem v2/v3: bank-conflict counter identical (2^21 = 0.85% of time)
// across all stagings -> conflicts were never the issue. v3's regression =
// per-iter global latency exposed serially inside the 2-barrier lockstep.
// Fix: re-split PV by q-rows (not channels). Each wave owns 16 q-rows for
// QK AND PV across all 256 channels -> P never crosses waves -> private
// 1.25KB LDS transpose slice per wave, ZERO s_barrier in the loop.
//  - V (8+8) issued at iter top, consumed in PV ~400cyc later.
//  - K(it+1)+mask(it+1) into ping-pong regs (compile-time parity), one full
//    iteration of latency cover. No sched_barrier / asm waitcnt anywhere.
//  - K/V addresses wave-invariant -> waves 2-4 L1-hit.
//  - acc[16] f32x4 (64 VGPR) + vf 64 + kf 48 + qf 12 ~> ~200 VGPR: (256,2).
// ---------------------------------------------------------------------------
__global__ __launch_bounds__(256, 2) void attn_kernel(
    const short* __restrict__ Q16, const short* __restrict__ K16,
    const short* __restrict__ V16t, const float* __restrict__ mask,
    short* __restrict__ Opart, float* __restrict__ Lpart)
{
    __shared__ short Ps[4 * 640];   // per-wave private 16x40 transpose slice

    const int tid = threadIdx.x;
    const int w = tid >> 6, lane = tid & 63, ln = lane & 15, quad = lane >> 4;
    const int bidx = blockIdx.x;
    const int kg = bidx >> 8;                       // 0..3 key group
    const int qg = bidx & 255;
    const int b  = (qg & 7) >> 1;                   // XCD-pinned batch
    const int qt = ((qg >> 3) << 1) | (qg & 1);     // 0..63
    const int q0 = qt * 64;
    const size_t bN = (size_t)b * NN;
    const size_t bCC = (size_t)b * CC;
    const int kbase = kg * 1024;
    const float C1 = 1.02062072615966f;             // 10/sqrt(96)
    short* myPs = &Ps[w * 640];

    bf16x8 qf[3];
    #pragma unroll
    for (int e = 0; e < 3; ++e)
        qf[e] = *(const bf16x8*)&Q16[(bN + q0 + w * 16 + ln) * EE + e * 32 + quad * 8];

    f32x4 acc[16];
    #pragma unroll
    for (int i = 0; i < 16; ++i) acc[i] = (f32x4){0.f, 0.f, 0.f, 0.f};
    float lsum[4] = {0.f, 0.f, 0.f, 0.f};

    bf16x8 kfA[6], kfB[6];
    float mkA0, mkA1, mkB0, mkB1;
    // prologue: K(0) + mask(0)
    #pragma unroll
    for (int e = 0; e < 3; ++e) {
        kfA[2 * e]     = *(const bf16x8*)&K16[(bN + kbase + ln) * EE + e * 32 + quad * 8];
        kfA[2 * e + 1] = *(const bf16x8*)&K16[(bN + kbase + 16 + ln) * EE + e * 32 + quad * 8];
    }
    mkA0 = mask[bN + kbase + ln];
    mkA1 = mask[bN + kbase + 16 + ln];

    auto iter = [&](int it, bf16x8* kfc, float mk0, float mk1,
                    bf16x8* kfn, float& nmk0, float& nmk1) {
        const int k0 = kbase + it * 32;

        // V first half: issued now, consumed in PV (QK+softmax+LDS of cover)
        bf16x8 vf0[8];
        #pragma unroll
        for (int nt = 0; nt < 8; ++nt)
            vf0[nt] = *(const bf16x8*)&V16t[(bCC + nt * 16 + ln) * NN + k0 + quad * 8];

        // ---- S = Q K^T (registers) ----
        f32x4 s0 = (f32x4){0.f,0.f,0.f,0.f}, s1 = s0;
        __builtin_amdgcn_s_setprio(1);
        #pragma unroll
        for (int e = 0; e < 3; ++e) {
            s0 = __builtin_amdgcn_mfma_f32_16x16x32_bf16(qf[e], kfc[2 * e],     s0, 0, 0, 0);
            s1 = __builtin_amdgcn_mfma_f32_16x16x32_bf16(qf[e], kfc[2 * e + 1], s1, 0, 0, 0);
        }
        __builtin_amdgcn_s_setprio(0);

        // V second half + next-iter K/mask prefetch (one full iter of cover)
        bf16x8 vf1[8];
        #pragma unroll
        for (int nt = 0; nt < 8; ++nt)
            vf1[nt] = *(const bf16x8*)&V16t[(bCC + (8 + nt) * 16 + ln) * NN + k0 + quad * 8];
        const int itn = (it + 1 < 32) ? it + 1 : it;
        const int k0n = kbase + itn * 32;
        #pragma unroll
        for (int e = 0; e < 3; ++e) {
            kfn[2 * e]     = *(const bf16x8*)&K16[(bN + k0n + ln) * EE + e * 32 + quad * 8];
            kfn[2 * e + 1] = *(const bf16x8*)&K16[(bN + k0n + 16 + ln) * EE + e * 32 + quad * 8];
        }
        nmk0 = mask[bN + k0n + ln];
        nmk1 = mask[bN + k0n + 16 + ln];

        // ---- softmax (fixed max = 1, associative) ----
        const bool z0 = mk0 >= 0.5f;
        const bool z1 = mk1 >= 0.5f;
        #pragma unroll
        for (int r = 0; r < 4; ++r) {
            float p0 = z0 ? 0.f : __expf(fmaf(s0[r], C1, -C1));
            float p1 = z1 ? 0.f : __expf(fmaf(s1[r], C1, -C1));
            lsum[r] += p0 + p1;
            myPs[(quad * 4 + r) * 40 + ln]      = f2bf(p0);
            myPs[(quad * 4 + r) * 40 + 16 + ln] = f2bf(p1);
        }
        // wave-private transpose readback (compiler inserts lgkmcnt ordering)
        bf16x8 pf = *(const bf16x8*)&myPs[ln * 40 + quad * 8];

        // ---- PV: this wave's 16 q-rows x all 256 channels ----
        __builtin_amdgcn_s_setprio(1);
        #pragma unroll
        for (int nt = 0; nt < 8; ++nt)
            acc[nt] = __builtin_amdgcn_mfma_f32_16x16x32_bf16(pf, vf0[nt], acc[nt], 0, 0, 0);
        #pragma unroll
        for (int nt = 0; nt < 8; ++nt)
            acc[8 + nt] = __builtin_amdgcn_mfma_f32_16x16x32_bf16(pf, vf1[nt], acc[8 + nt], 0, 0, 0);
        __builtin_amdgcn_s_setprio(0);
    };

    #pragma unroll 1
    for (int it2 = 0; it2 < 16; ++it2) {
        iter(2 * it2,     kfA, mkA0, mkA1, kfB, mkB0, mkB1);
        iter(2 * it2 + 1, kfB, mkB0, mkB1, kfA, mkA0, mkA1);
    }

    // ---- epilogue: partial l and partial O ----
    #pragma unroll
    for (int r = 0; r < 4; ++r) {
        float l = lsum[r];
        l += __shfl_xor(l, 1, 64); l += __shfl_xor(l, 2, 64);
        l += __shfl_xor(l, 4, 64); l += __shfl_xor(l, 8, 64);
        if (ln == 0)
            Lpart[(size_t)kg * NTOT + bN + q0 + w * 16 + quad * 4 + r] = l;
    }
    #pragma unroll
    for (int nt = 0; nt < 16; ++nt)
        #pragma unroll
        for (int r = 0; r < 4; ++r)
            Opart[((size_t)kg * NTOT + bN + q0 + w * 16 + quad * 4 + r) * 256
                  + nt * 16 + ln] = f2bf(acc[nt][r]);
}

// ---------------------------------------------------------------------------
// Kernel 5: mega-fused epilogue. 32 rows/block, grid 512 (2 blocks/CU).
// P1: O = (sum of 4 Opart)/l -> Olds; Xnm -> Dlds upper.
// P2: D1 = O@wo^T - Xt -> Dlds lower.  P3: Hid = gelu([D1|Xnm]@wd1^T) -> Hlds.
// P4: Cor = Hid@wd2^T -> Clds.  P5: gate GEMM + delta -> tileB; out = x+delta.
// Weights read direct from L2 (no staging, no in-GEMM barriers).
// ---------------------------------------------------------------------------
__global__ __launch_bounds__(256, 2) void epi_kernel(
    const short* __restrict__ Opart, const float* __restrict__ Lpart,
    const short* __restrict__ W16, const short* __restrict__ Xt16,
    const short* __restrict__ Xn16, const float* __restrict__ mask,
    const float* __restrict__ rs, const float* __restrict__ x,
    float* __restrict__ out)
{
    __shared__ char lds[54400];
    short* Olds  = (short*)lds;              // stride 264, rows 0..31 (P1-P2)
    short* Hlds  = (short*)lds;              // stride 264 (P3-P4, Olds dead)
    short* Dlds  = (short*)(lds + 16896);    // stride 528, [D1 | Xnm] (P1-P3)
    short* Clds  = (short*)(lds + 16896);    // stride 264 (P4+, Dlds dead)
    short* tileB = (short*)(lds + 33792);    // 256 x 40 (P5, upper arena dead)
    float* lsh   = (float*)(lds + 54272);    // 32

    const int tid = threadIdx.x;
    const int w = tid >> 6, lane = tid & 63, ln = lane & 15, quad = lane >> 4;
    const int wm = w >> 1, wn = w & 1;
    const int m0 = blockIdx.x * 32;
    const int b = m0 >> 12, p0l = m0 & 4095;

    if (tid < 32) {
        int g = m0 + tid;
        lsh[tid] = 1.0f / (Lpart[g] + Lpart[NTOT + g] + Lpart[2 * NTOT + g] + Lpart[3 * NTOT + g]);
    }
    __syncthreads();

    // ---- P1 ----
    #pragma unroll
    for (int i = 0; i < 4; ++i) {
        int idx = tid + i * 256;
        int q = idx >> 5, ch8 = (idx & 31) * 8;
        size_t base = (size_t)(m0 + q) * 256 + ch8;
        bf16x8 a0 = *(const bf16x8*)&Opart[base];
        bf16x8 a1 = *(const bf16x8*)&Opart[(size_t)NTOT * 256 + base];
        bf16x8 a2 = *(const bf16x8*)&Opart[(size_t)2 * NTOT * 256 + base];
        bf16x8 a3 = *(const bf16x8*)&Opart[(size_t)3 * NTOT * 256 + base];
        float linv = lsh[q];
        bf16x8 o;
        #pragma unroll
        for (int e = 0; e < 8; ++e)
            o[e] = f2bf((bf2f(a0[e]) + bf2f(a1[e]) + bf2f(a2[e]) + bf2f(a3[e])) * linv);
        *(bf16x8*)&Olds[q * 264 + ch8] = o;
        bf16x8 xn = *(const bf16x8*)&Xn16[base];
        float mq = mask[m0 + q];
        bf16x8 xm;
        #pragma unroll
        for (int e = 0; e < 8; ++e) xm[e] = f2bf(bf2f(xn[e]) * mq);
        *(bf16x8*)&Dlds[q * 528 + 256 + ch8] = xm;
    }
    __syncthreads();

    // ---- P2: D1 = O@wo^T - Xt ----
    {
        f32x4 acc[8];
        #pragma unroll
        for (int i = 0; i < 8; ++i) acc[i] = (f32x4){0.f, 0.f, 0.f, 0.f};
        #pragma unroll
        for (int kt = 0; kt < 8; ++kt) {
            bf16x8 af = *(const bf16x8*)&Olds[(wm * 16 + ln) * 264 + kt * 32 + quad * 8];
            #pragma unroll
            for (int nt = 0; nt < 8; ++nt) {
                int col = wn * 128 + nt * 16 + ln;
                bf16x8 bf = *(const bf16x8*)&W16[OFF_WO + (size_t)col * 256 + kt * 32 + quad * 8];
                acc[nt] = __builtin_amdgcn_mfma_f32_16x16x32_bf16(af, bf, acc[nt], 0, 0, 0);
            }
        }
        #pragma unroll
        for (int nt = 0; nt < 8; ++nt) {
            int col = wn * 128 + nt * 16 + ln;
            #pragma unroll
            for (int r = 0; r < 4; ++r) {
                int row = wm * 16 + quad * 4 + r;
                float v = acc[nt][r] - bf2f(Xt16[(size_t)(m0 + row) * 256 + col]);
                Dlds[row * 528 + col] = f2bf(v);
            }
        }
    }
    __syncthreads();

    // ---- P3: Hid = gelu([D1|Xnm] @ wd1^T) ----
    {
        f32x4 acc[8];
        #pragma unroll
        for (int i = 0; i < 8; ++i) acc[i] = (f32x4){0.f, 0.f, 0.f, 0.f};
        #pragma unroll
        for (int kt = 0; kt < 16; ++kt) {
            bf16x8 af = *(const bf16x8*)&Dlds[(wm * 16 + ln) * 528 + kt * 32 + quad * 8];
            #pragma unroll
            for (int nt = 0; nt < 8; ++nt) {
                int col = wn * 128 + nt * 16 + ln;
                bf16x8 bf = *(const bf16x8*)&W16[OFF_WD1 + (size_t)col * 512 + kt * 32 + quad * 8];
                acc[nt] = __builtin_amdgcn_mfma_f32_16x16x32_bf16(af, bf, acc[nt], 0, 0, 0);
            }
        }
        __syncthreads();   // Olds reads done block-wide before Hlds overwrite
        #pragma unroll
        for (int nt = 0; nt < 8; ++nt) {
            int col = wn * 128 + nt * 16 + ln;
            #pragma unroll
            for (int r = 0; r < 4; ++r) {
                int row = wm * 16 + quad * 4 + r;
                Hlds[row * 264 + col] = f2bf(gelu_exact(acc[nt][r]));
            }
        }
    }
    __syncthreads();

    // ---- P4: Cor = Hid @ wd2^T ----
    {
        f32x4 acc[8];
        #pragma unroll
        for (int i = 0; i < 8; ++i) acc[i] = (f32x4){0.f, 0.f, 0.f, 0.f};
        #pragma unroll
        for (int kt = 0; kt < 8; ++kt) {
            bf16x8 af = *(const bf16x8*)&Hlds[(wm * 16 + ln) * 264 + kt * 32 + quad * 8];
            #pragma unroll
            for (int nt = 0; nt < 8; ++nt) {
                int col = wn * 128 + nt * 16 + ln;
                bf16x8 bf = *(const bf16x8*)&W16[OFF_WD2 + (size_t)col * 256 + kt * 32 + quad * 8];
                acc[nt] = __builtin_amdgcn_mfma_f32_16x16x32_bf16(af, bf, acc[nt], 0, 0, 0);
            }
        }
        __syncthreads();   // Dlds reads done before Clds overwrite
        #pragma unroll
        for (int nt = 0; nt < 8; ++nt) {
            int col = wn * 128 + nt * 16 + ln;
            #pragma unroll
            for (int r = 0; r < 4; ++r) {
                int row = wm * 16 + quad * 4 + r;
                Clds[row * 264 + col] = f2bf(acc[nt][r]);
            }
        }
    }
    __syncthreads();

    // ---- P5: gate GEMM + delta ----
    {
        f32x4 acc[8];
        #pragma unroll
        for (int i = 0; i < 8; ++i) acc[i] = (f32x4){0.f, 0.f, 0.f, 0.f};
        #pragma unroll
        for (int kt = 0; kt < 8; ++kt) {
            bf16x8 af = *(const bf16x8*)&Clds[(wm * 16 + ln) * 264 + kt * 32 + quad * 8];
            #pragma unroll
            for (int nt = 0; nt < 8; ++nt) {
                int col = wn * 128 + nt * 16 + ln;
                bf16x8 bf = *(const bf16x8*)&W16[OFF_WG + (size_t)col * 256 + kt * 32 + quad * 8];
                acc[nt] = __builtin_amdgcn_mfma_f32_16x16x32_bf16(af, bf, acc[nt], 0, 0, 0);
            }
        }
        float trs = tanhf(rs[0]);
        #pragma unroll
        for (int nt = 0; nt < 8; ++nt) {
            int col = wn * 128 + nt * 16 + ln;
            float wgl = bf2f(W16[OFF_WGL + col]);
            #pragma unroll
            for (int r = 0; r < 4; ++r) {
                int row = wm * 16 + quad * 4 + r;
                float mrow = mask[m0 + row];
                float logit = acc[nt][r] + mrow * wgl;
                float gate = mrow / (1.0f + __expf(-logit));
                float corr = bf2f(Clds[row * 264 + col]);
                tileB[col * 40 + row] = f2bf(trs * gate * corr);
            }
        }
    }
    __syncthreads();

    // ---- store: out[b,ch,p] = x + delta ----
    #pragma unroll
    for (int i = 0; i < 4; ++i) {
        int idx = tid + i * 256;
        int ch = idx >> 2, p8 = (idx & 3) * 8;
        bf16x8 d = *(const bf16x8*)&tileB[ch * 40 + p8];
        size_t o = ((size_t)b * CC + ch) * NN + p0l + p8;
        float4 x0 = *(const float4*)&x[o];
        float4 x1 = *(const float4*)&x[o + 4];
        float4 o0, o1;
        o0.x = x0.x + bf2f(d[0]); o0.y = x0.y + bf2f(d[1]);
        o0.z = x0.z + bf2f(d[2]); o0.w = x0.w + bf2f(d[3]);
        o1.x = x1.x + bf2f(d[4]); o1.y = x1.y + bf2f(d[5]);
        o1.z = x1.z + bf2f(d[6]); o1.w = x1.w + bf2f(d[7]);
        *(float4*)&out[o] = o0;
        *(float4*)&out[o + 4] = o1;
    }
}

// ---------------------------------------------------------------------------
extern "C" void kernel_launch(void* const* d_in, const int* in_sizes, int n_in,
                              void* d_out, int out_size, void* d_ws, size_t ws_size,
                              hipStream_t stream) {
    const float* x     = (const float*)d_in[0];
    const float* mask  = (const float*)d_in[1];
    const float* gamma = (const float*)d_in[2];
    const float* beta  = (const float*)d_in[3];
    const float* wq    = (const float*)d_in[4];
    const float* wk    = (const float*)d_in[5];
    const float* wv    = (const float*)d_in[6];
    const float* w_out = (const float*)d_in[7];
    const float* w_qm  = (const float*)d_in[8];
    const float* wd1   = (const float*)d_in[9];
    const float* wd2   = (const float*)d_in[10];
    const float* wg    = (const float*)d_in[11];
    const float* rs    = (const float*)d_in[12];
    float* out = (float*)d_out;

    const size_t NC = (size_t)NTOT * CC;
    const size_t NE = (size_t)NTOT * EE;
    short* Xn16  = (short*)d_ws;        // NC
    short* Xt16  = Xn16 + NC;           // NC
    short* Q16   = Xt16 + NC;           // NE
    short* K16   = Q16 + NE;            // NE
    short* V16t  = K16 + NE;            // NC
    short* W16   = V16t + NC;           // W16_TOTAL
    short* Opart = W16 + W16_TOTAL;     // 4*NC
    float* Lpart = (float*)(Opart + 4 * NC);   // 4*NTOT f32
    // ~66 MB total

    wconv_kernel<<<(W16_TOTAL + 255) / 256, 256, 0, stream>>>(wq, wk, wv, w_out,
                                                              wd1, wd2, wg, W16);
    ln_kernel<<<512, 256, 0, stream>>>(x, gamma, beta, Xt16, Xn16);
    qkproj_kernel<<<512, 256, 0, stream>>>(Xn16, W16, mask, w_qm, Q16, K16);
    vproj_kernel<<<512, 256, 0, stream>>>(Xt16, W16, V16t);
    attn_kernel<<<1024, 256, 0, stream>>>(Q16, K16, V16t, mask, Opart, Lpart);
    epi_kernel<<<512, 256, 0, stream>>>(Opart, Lpart, W16, Xt16, Xn16, mask,
                                        rs, x, out);
}

// Round 4
// 298.116 us; speedup vs baseline: 1.6445x; 1.6445x over previous
//
#include <hip/hip_runtime.h>
#include <hip/hip_bf16.h>
#include <math.h>

// Problem constants
#define BB 4
#define CC 256
#define NN 4096          // H*W
#define EE 96
#define NTOT (BB*NN)     // 16384 rows

typedef __attribute__((ext_vector_type(8))) short bf16x8;
typedef __attribute__((ext_vector_type(4))) float f32x4;

__device__ __forceinline__ short f2bf(float x) {
    __hip_bfloat16 h = __float2bfloat16(x);
    return *reinterpret_cast<short*>(&h);
}
__device__ __forceinline__ float bf2f(short s) {
    unsigned int u = ((unsigned int)(unsigned short)s) << 16;
    float f;
    __builtin_memcpy(&f, &u, 4);
    return f;
}
__device__ __forceinline__ float gelu_exact(float v) {
    return 0.5f * v * (1.0f + erff(v * 0.70710678118654752f));
}
// async global->LDS, 16B per lane; LDS dest = uniform base + lane*16
__device__ __forceinline__ void gld16(void* lds, const void* g) {
    __builtin_amdgcn_global_load_lds(
        (const __attribute__((address_space(1))) unsigned int*)g,
        (__attribute__((address_space(3))) unsigned int*)lds, 16, 0, 0);
}

// Weight arena offsets (shorts). wg split into 256-stride matrix + last col.
#define OFF_WQ  0
#define OFF_WK  24576
#define OFF_WV  49152
#define OFF_WO  114688
#define OFF_WD1 180224
#define OFF_WD2 311296
#define OFF_WG  376832
#define OFF_WGL 442368
#define W16_TOTAL 442624

// ---------------------------------------------------------------------------
// Kernel 1: channel LayerNorm + transpose, 32-position tiles (4 blocks/CU).
// Emits bf16 Xt16 (= x, row-major) and Xn16 (normed).
// v5: weight fp32->bf16 conversion folded in as a grid-stride prologue
// (no dependency on ln's own work; W16 consumed only by later kernels).
// ---------------------------------------------------------------------------
__global__ __launch_bounds__(256) void ln_kernel(
    const float* __restrict__ x, const float* __restrict__ gamma,
    const float* __restrict__ beta,
    const float* __restrict__ wq, const float* __restrict__ wk,
    const float* __restrict__ wv, const float* __restrict__ wo,
    const float* __restrict__ wd1, const float* __restrict__ wd2,
    const float* __restrict__ wg, short* __restrict__ W16,
    short* __restrict__ Xt16, short* __restrict__ Xn16) {
    __shared__ float tile[256 * 33];
    __shared__ float psum[8][32], psq[8][32];
    __shared__ float mu_s[32], rs_s[32];
    __shared__ float gs[256], bs[256];
    const int b  = blockIdx.x >> 7;
    const int p0 = (blockIdx.x & 127) * 32;
    const int tid = threadIdx.x;
    const float* xb = x + (size_t)b * CC * NN;

    // ---- folded weight conversion (grid-stride, 4 iters) ----
    for (int i = blockIdx.x * 256 + tid; i < W16_TOTAL; i += 512 * 256) {
        float v;
        if      (i < OFF_WK)  v = wq[i];
        else if (i < OFF_WV)  v = wk[i - OFF_WK];
        else if (i < OFF_WO)  v = wv[i - OFF_WV];
        else if (i < OFF_WD1) v = wo[i - OFF_WO];
        else if (i < OFF_WD2) v = wd1[i - OFF_WD1];
        else if (i < OFF_WG)  v = wd2[i - OFF_WD2];
        else if (i < OFF_WGL) { int l = i - OFF_WG; v = wg[(l >> 8) * 257 + (l & 255)]; }
        else                  v = wg[(i - OFF_WGL) * 257 + 256];
        W16[i] = f2bf(v);
    }

    gs[tid] = gamma[tid];
    bs[tid] = beta[tid];
    #pragma unroll
    for (int i = 0; i < 8; ++i) {
        int idx = tid + i * 256;
        int c = idx >> 3, p4 = (idx & 7) * 4;
        float4 v = *(const float4*)&xb[(size_t)c * NN + p0 + p4];
        tile[c * 33 + p4]     = v.x;
        tile[c * 33 + p4 + 1] = v.y;
        tile[c * 33 + p4 + 2] = v.z;
        tile[c * 33 + p4 + 3] = v.w;
    }
    __syncthreads();
    {
        int col = tid & 31, part = tid >> 5;
        float s = 0.f, sq = 0.f;
        for (int r = part * 32; r < part * 32 + 32; ++r) {
            float v = tile[r * 33 + col];
            s += v; sq += v * v;
        }
        psum[part][col] = s; psq[part][col] = sq;
    }
    __syncthreads();
    if (tid < 32) {
        float S = 0.f, SQ = 0.f;
        #pragma unroll
        for (int j = 0; j < 8; ++j) { S += psum[j][tid]; SQ += psq[j][tid]; }
        float mu = S / 256.0f;
        float var = SQ / 256.0f - mu * mu;
        mu_s[tid] = mu;
        rs_s[tid] = rsqrtf(var + 1e-5f);
    }
    __syncthreads();
    size_t rowbase = ((size_t)b * NN + p0) * CC;
    #pragma unroll
    for (int i = 0; i < 4; ++i) {
        int idx = tid + i * 256;
        int p = idx >> 5, c8 = (idx & 31) * 8;
        float mu = mu_s[p], rcp = rs_s[p];
        bf16x8 xt, xn;
        #pragma unroll
        for (int j = 0; j < 8; ++j) {
            float v = tile[(c8 + j) * 33 + p];
            float n = (v - mu) * rcp * gs[c8 + j] + bs[c8 + j];
            xt[j] = f2bf(v); xn[j] = f2bf(n);
        }
        size_t o = rowbase + (size_t)p * CC + c8;
        *(bf16x8*)&Xt16[o] = xt;
        *(bf16x8*)&Xn16[o] = xn;
    }
}

// ---------------------------------------------------------------------------
// Kernel 2 (fused): Q+K projection (blocks 0..511) and V projection
// (blocks 512..1023) in ONE launch -> 4 mixed blocks/CU instead of two
// sequential 2-block/CU launches. Bodies identical to the split kernels.
// ---------------------------------------------------------------------------
__global__ __launch_bounds__(256) void proj_kernel(
    const short* __restrict__ Xn16, const short* __restrict__ Xt16,
    const short* __restrict__ W16,
    const float* __restrict__ mask, const float* __restrict__ w_qm,
    short* __restrict__ Q16, short* __restrict__ K16,
    short* __restrict__ V16t)
{
    __shared__ short Vt[256 * 40];
    const int tid = threadIdx.x;
    const int w = tid >> 6, lane = tid & 63, ln = lane & 15, quad = lane >> 4;

    if (blockIdx.x < 512) {
        // ---- Q+K projection + cosine norm ----
        const int m0 = blockIdx.x * 32 + (w & 1) * 16;
        const bool isQ = (w < 2);
        const int woff = isQ ? OFF_WQ : OFF_WK;

        f32x4 acc[6];
        #pragma unroll
        for (int i = 0; i < 6; ++i) acc[i] = (f32x4){0.f, 0.f, 0.f, 0.f};

        #pragma unroll
        for (int kt = 0; kt < 8; ++kt) {
            bf16x8 af = *(const bf16x8*)&Xn16[(size_t)(m0 + ln) * 256 + kt * 32 + quad * 8];
            #pragma unroll
            for (int nt = 0; nt < 6; ++nt) {
                bf16x8 bf = *(const bf16x8*)&W16[woff + (size_t)(nt * 16 + ln) * 256 + kt * 32 + quad * 8];
                acc[nt] = __builtin_amdgcn_mfma_f32_16x16x32_bf16(af, bf, acc[nt], 0, 0, 0);
            }
        }

        short* outp = isQ ? Q16 : K16;
        #pragma unroll
        for (int r = 0; r < 4; ++r) {
            int row = m0 + quad * 4 + r;
            float mrow = isQ ? mask[row] : 0.f;
            float vals[6];
            float ss = 0.f;
            #pragma unroll
            for (int nt = 0; nt < 6; ++nt) {
                float v = acc[nt][r];
                if (isQ) v += mrow * w_qm[nt * 16 + ln];
                vals[nt] = v;
                ss += v * v;
            }
            ss += __shfl_xor(ss, 1, 64); ss += __shfl_xor(ss, 2, 64);
            ss += __shfl_xor(ss, 4, 64); ss += __shfl_xor(ss, 8, 64);
            float sc = 1.0f / fmaxf(sqrtf(ss), 1e-12f);
            #pragma unroll
            for (int nt = 0; nt < 6; ++nt)
                outp[(size_t)row * EE + nt * 16 + ln] = f2bf(vals[nt] * sc);
        }
    } else {
        // ---- V projection, transposed store ----
        const int m0 = (blockIdx.x - 512) * 32;
        const int wm = w >> 1, wn = w & 1;
        const int mrow = m0 + wm * 16;

        f32x4 acc[8];
        #pragma unroll
        for (int i = 0; i < 8; ++i) acc[i] = (f32x4){0.f, 0.f, 0.f, 0.f};

        #pragma unroll
        for (int kt = 0; kt < 8; ++kt) {
            bf16x8 af = *(const bf16x8*)&Xt16[(size_t)(mrow + ln) * 256 + kt * 32 + quad * 8];
            #pragma unroll
            for (int nt = 0; nt < 8; ++nt) {
                int col = wn * 128 + nt * 16 + ln;
                bf16x8 bf = *(const bf16x8*)&W16[OFF_WV + (size_t)col * 256 + kt * 32 + quad * 8];
                acc[nt] = __builtin_amdgcn_mfma_f32_16x16x32_bf16(af, bf, acc[nt], 0, 0, 0);
            }
        }
        #pragma unroll
        for (int nt = 0; nt < 8; ++nt) {
            int ch = wn * 128 + nt * 16 + ln;
            #pragma unroll
            for (int r = 0; r < 4; ++r)
                Vt[ch * 40 + wm * 16 + quad * 4 + r] = f2bf(acc[nt][r]);
        }
        __syncthreads();
        const int b = m0 >> 12, p0l = m0 & 4095;
        #pragma unroll
        for (int i = 0; i < 4; ++i) {
            int idx = tid + i * 256;
            int ch = idx >> 2, p8 = (idx & 3) * 8;
            *(bf16x8*)&V16t[((size_t)b * CC + ch) * NN + p0l + p8] =
                *(const bf16x8*)&Vt[ch * 40 + p8];
        }
    }
}

// ---------------------------------------------------------------------------
// Kernel 3: MFMA attention, 4-way K-split. v5 = v2 (best measured, 99.5us)
// + SINGLE barrier per iteration via Ps double-buffer.
// Safety argument (reuse distance 2 iters = 2 barriers):
//   [it: W_Ps(c), bar, R_Ps(c)] [it+1: W_Ps(n), bar, R_Ps(n)] [it+2: W_Ps(c)..]
//   a wave at W_Ps(c)@it+2 passed bar@it+1 => all waves finished R_Ps(c)@it.
//   Same argument covers Ks: DMA(it+1)->Ks[n] issued at top of it (after
//   bar@it-1, where Ks[n] was last read) and drained by vmcnt(0)+bar@it,
//   read at QK@it+1 after that barrier.
// K via global_load_lds dbuf (proven), V direct global->reg (proven),
// mask direct (proven). LDS 22.5KB, ~64 VGPR + 64 AGPR -> 4 blocks/CU.
// ---------------------------------------------------------------------------
__global__ __launch_bounds__(256, 4) void attn_kernel(
    const short* __restrict__ Q16, const short* __restrict__ K16,
    const short* __restrict__ V16t, const float* __restrict__ mask,
    short* __restrict__ Opart, float* __restrict__ Lpart)
{
    __shared__ short Ks[2][3072];     // [buf][p 0..11][key 0..31] chunks of 8 shorts
    __shared__ short Ps[2][2560];     // [buf][64 rows][40] (stride-40 padded)

    const int tid = threadIdx.x;
    const int w = tid >> 6, lane = tid & 63, ln = lane & 15, quad = lane >> 4;
    const int bidx = blockIdx.x;
    const int kg = bidx >> 8;                       // 0..3 key group
    const int qg = bidx & 255;
    const int b  = (qg & 7) >> 1;                   // XCD-pinned batch
    const int qt = ((qg >> 3) << 1) | (qg & 1);     // 0..63
    const int q0 = qt * 64;
    const size_t bN = (size_t)b * NN;
    const size_t bCC = (size_t)b * CC;
    const int kbase = kg * 1024;
    const float C1 = 1.02062072615966f;             // 10/sqrt(96)
    const int wbase = w * 64;

    bf16x8 qf[3];
    #pragma unroll
    for (int e = 0; e < 3; ++e)
        qf[e] = *(const bf16x8*)&Q16[(bN + q0 + w * 16 + ln) * EE + e * 32 + quad * 8];

    f32x4 acc[4][4];
    #pragma unroll
    for (int mt = 0; mt < 4; ++mt)
        #pragma unroll
        for (int nt = 0; nt < 4; ++nt) acc[mt][nt] = (f32x4){0.f, 0.f, 0.f, 0.f};
    float lsum[4] = {0.f, 0.f, 0.f, 0.f};

    // prologue: K(0) into Ks[0]
    gld16(&Ks[0][wbase * 8], &K16[(bN + kbase + (tid & 31)) * EE + (tid >> 5) * 8]);
    if (w < 2)
        gld16(&Ks[0][(256 + wbase) * 8],
              &K16[(bN + kbase + (tid & 31)) * EE + (8 + (tid >> 5)) * 8]);
    __syncthreads();   // full drain ok in prologue

    for (int it = 0; it < 32; ++it) {
        const int k0 = kbase + it * 32;
        const int cur = it & 1;

        // K(it+1) prefetch into the other Ks buffer (drained at this iter's
        // single barrier; read only after that barrier, at QK of it+1).
        if (it + 1 < 32) {
            const int k0n = k0 + 32;
            gld16(&Ks[cur ^ 1][wbase * 8],
                  &K16[(bN + k0n + (tid & 31)) * EE + (tid >> 5) * 8]);
            if (w < 2)
                gld16(&Ks[cur ^ 1][(256 + wbase) * 8],
                      &K16[(bN + k0n + (tid & 31)) * EE + (8 + (tid >> 5)) * 8]);
        }
        // V fragments direct global->reg; consumed in PV after the barrier.
        bf16x8 vf[4];
        #pragma unroll
        for (int nt = 0; nt < 4; ++nt)
            vf[nt] = *(const bf16x8*)&V16t[(bCC + wbase + nt * 16 + ln) * NN + k0 + quad * 8];
        const float mk0 = mask[bN + k0 + ln];
        const float mk1 = mask[bN + k0 + 16 + ln];

        // ---- S = Q K^T (K from LDS buffer cur) ----
        f32x4 s0 = (f32x4){0.f,0.f,0.f,0.f}, s1 = s0;
        __builtin_amdgcn_s_setprio(1);
        #pragma unroll
        for (int e = 0; e < 3; ++e) {
            bf16x8 kf0 = *(const bf16x8*)&Ks[cur][((e * 4 + quad) * 32 + ln) * 8];
            bf16x8 kf1 = *(const bf16x8*)&Ks[cur][((e * 4 + quad) * 32 + 16 + ln) * 8];
            s0 = __builtin_amdgcn_mfma_f32_16x16x32_bf16(qf[e], kf0, s0, 0, 0, 0);
            s1 = __builtin_amdgcn_mfma_f32_16x16x32_bf16(qf[e], kf1, s1, 0, 0, 0);
        }
        __builtin_amdgcn_s_setprio(0);
        const bool z0 = mk0 >= 0.5f;
        const bool z1 = mk1 >= 0.5f;
        #pragma unroll
        for (int r = 0; r < 4; ++r) {
            float p0 = z0 ? 0.f : __expf(fmaf(s0[r], C1, -C1));
            float p1 = z1 ? 0.f : __expf(fmaf(s1[r], C1, -C1));
            lsum[r] += p0 + p1;
            Ps[cur][(w * 16 + quad * 4 + r) * 40 + ln]      = f2bf(p0);
            Ps[cur][(w * 16 + quad * 4 + r) * 40 + 16 + ln] = f2bf(p1);
        }
        // ---- the ONE barrier: publishes Ps(cur), drains K-DMA(it+1) ----
        asm volatile("s_waitcnt vmcnt(0) lgkmcnt(0)" ::: "memory");
        __builtin_amdgcn_s_barrier();
        __builtin_amdgcn_sched_barrier(0);

        // ---- PV: all 64 q x this wave's 64 channels; V from registers ----
        __builtin_amdgcn_s_setprio(1);
        #pragma unroll
        for (int mt = 0; mt < 4; ++mt) {
            bf16x8 pf = *(const bf16x8*)&Ps[cur][(mt * 16 + ln) * 40 + quad * 8];
            #pragma unroll
            for (int nt = 0; nt < 4; ++nt)
                acc[mt][nt] = __builtin_amdgcn_mfma_f32_16x16x32_bf16(pf, vf[nt], acc[mt][nt], 0, 0, 0);
        }
        __builtin_amdgcn_s_setprio(0);
        // no end-of-iter barrier: next iter writes the OTHER Ps/Ks buffers.
    }

    // ---- epilogue: partial l and partial O ----
    #pragma unroll
    for (int r = 0; r < 4; ++r) {
        float l = lsum[r];
        l += __shfl_xor(l, 1, 64); l += __shfl_xor(l, 2, 64);
        l += __shfl_xor(l, 4, 64); l += __shfl_xor(l, 8, 64);
        if (ln == 0)
            Lpart[(size_t)kg * NTOT + bN + q0 + w * 16 + quad * 4 + r] = l;
    }
    #pragma unroll
    for (int mt = 0; mt < 4; ++mt)
        #pragma unroll
        for (int nt = 0; nt < 4; ++nt)
            #pragma unroll
            for (int r = 0; r < 4; ++r)
                Opart[((size_t)kg * NTOT + bN + q0 + mt * 16 + quad * 4 + r) * 256
                      + wbase + nt * 16 + ln] = f2bf(acc[mt][nt][r]);
}

// ---------------------------------------------------------------------------
// Kernel 4: mega-fused epilogue. 32 rows/block, grid 512 (2 blocks/CU).
// P1: O = (sum of 4 Opart)/l -> Olds; Xnm -> Dlds upper.
// P2: D1 = O@wo^T - Xt -> Dlds lower.  P3: Hid = gelu([D1|Xnm]@wd1^T) -> Hlds.
// P4: Cor = Hid@wd2^T -> Clds.  P5: gate GEMM + delta -> tileB; out = x+delta.
// Weights read direct from L2 (no staging, no in-GEMM barriers).
// ---------------------------------------------------------------------------
__global__ __launch_bounds__(256, 2) void epi_kernel(
    const short* __restrict__ Opart, const float* __restrict__ Lpart,
    const short* __restrict__ W16, const short* __restrict__ Xt16,
    const short* __restrict__ Xn16, const float* __restrict__ mask,
    const float* __restrict__ rs, const float* __restrict__ x,
    float* __restrict__ out)
{
    __shared__ char lds[54400];
    short* Olds  = (short*)lds;              // stride 264, rows 0..31 (P1-P2)
    short* Hlds  = (short*)lds;              // stride 264 (P3-P4, Olds dead)
    short* Dlds  = (short*)(lds + 16896);    // stride 528, [D1 | Xnm] (P1-P3)
    short* Clds  = (short*)(lds + 16896);    // stride 264 (P4+, Dlds dead)
    short* tileB = (short*)(lds + 33792);    // 256 x 40 (P5, upper arena dead)
    float* lsh   = (float*)(lds + 54272);    // 32

    const int tid = threadIdx.x;
    const int w = tid >> 6, lane = tid & 63, ln = lane & 15, quad = lane >> 4;
    const int wm = w >> 1, wn = w & 1;
    const int m0 = blockIdx.x * 32;
    const int b = m0 >> 12, p0l = m0 & 4095;

    if (tid < 32) {
        int g = m0 + tid;
        lsh[tid] = 1.0f / (Lpart[g] + Lpart[NTOT + g] + Lpart[2 * NTOT + g] + Lpart[3 * NTOT + g]);
    }
    __syncthreads();

    // ---- P1 ----
    #pragma unroll
    for (int i = 0; i < 4; ++i) {
        int idx = tid + i * 256;
        int q = idx >> 5, ch8 = (idx & 31) * 8;
        size_t base = (size_t)(m0 + q) * 256 + ch8;
        bf16x8 a0 = *(const bf16x8*)&Opart[base];
        bf16x8 a1 = *(const bf16x8*)&Opart[(size_t)NTOT * 256 + base];
        bf16x8 a2 = *(const bf16x8*)&Opart[(size_t)2 * NTOT * 256 + base];
        bf16x8 a3 = *(const bf16x8*)&Opart[(size_t)3 * NTOT * 256 + base];
        float linv = lsh[q];
        bf16x8 o;
        #pragma unroll
        for (int e = 0; e < 8; ++e)
            o[e] = f2bf((bf2f(a0[e]) + bf2f(a1[e]) + bf2f(a2[e]) + bf2f(a3[e])) * linv);
        *(bf16x8*)&Olds[q * 264 + ch8] = o;
        bf16x8 xn = *(const bf16x8*)&Xn16[base];
        float mq = mask[m0 + q];
        bf16x8 xm;
        #pragma unroll
        for (int e = 0; e < 8; ++e) xm[e] = f2bf(bf2f(xn[e]) * mq);
        *(bf16x8*)&Dlds[q * 528 + 256 + ch8] = xm;
    }
    __syncthreads();

    // ---- P2: D1 = O@wo^T - Xt ----
    {
        f32x4 acc[8];
        #pragma unroll
        for (int i = 0; i < 8; ++i) acc[i] = (f32x4){0.f, 0.f, 0.f, 0.f};
        #pragma unroll
        for (int kt = 0; kt < 8; ++kt) {
            bf16x8 af = *(const bf16x8*)&Olds[(wm * 16 + ln) * 264 + kt * 32 + quad * 8];
            #pragma unroll
            for (int nt = 0; nt < 8; ++nt) {
                int col = wn * 128 + nt * 16 + ln;
                bf16x8 bf = *(const bf16x8*)&W16[OFF_WO + (size_t)col * 256 + kt * 32 + quad * 8];
                acc[nt] = __builtin_amdgcn_mfma_f32_16x16x32_bf16(af, bf, acc[nt], 0, 0, 0);
            }
        }
        #pragma unroll
        for (int nt = 0; nt < 8; ++nt) {
            int col = wn * 128 + nt * 16 + ln;
            #pragma unroll
            for (int r = 0; r < 4; ++r) {
                int row = wm * 16 + quad * 4 + r;
                float v = acc[nt][r] - bf2f(Xt16[(size_t)(m0 + row) * 256 + col]);
                Dlds[row * 528 + col] = f2bf(v);
            }
        }
    }
    __syncthreads();

    // ---- P3: Hid = gelu([D1|Xnm] @ wd1^T) ----
    {
        f32x4 acc[8];
        #pragma unroll
        for (int i = 0; i < 8; ++i) acc[i] = (f32x4){0.f, 0.f, 0.f, 0.f};
        #pragma unroll
        for (int kt = 0; kt < 16; ++kt) {
            bf16x8 af = *(const bf16x8*)&Dlds[(wm * 16 + ln) * 528 + kt * 32 + quad * 8];
            #pragma unroll
            for (int nt = 0; nt < 8; ++nt) {
                int col = wn * 128 + nt * 16 + ln;
                bf16x8 bf = *(const bf16x8*)&W16[OFF_WD1 + (size_t)col * 512 + kt * 32 + quad * 8];
                acc[nt] = __builtin_amdgcn_mfma_f32_16x16x32_bf16(af, bf, acc[nt], 0, 0, 0);
            }
        }
        __syncthreads();   // Olds reads done block-wide before Hlds overwrite
        #pragma unroll
        for (int nt = 0; nt < 8; ++nt) {
            int col = wn * 128 + nt * 16 + ln;
            #pragma unroll
            for (int r = 0; r < 4; ++r) {
                int row = wm * 16 + quad * 4 + r;
                Hlds[row * 264 + col] = f2bf(gelu_exact(acc[nt][r]));
            }
        }
    }
    __syncthreads();

    // ---- P4: Cor = Hid @ wd2^T ----
    {
        f32x4 acc[8];
        #pragma unroll
        for (int i = 0; i < 8; ++i) acc[i] = (f32x4){0.f, 0.f, 0.f, 0.f};
        #pragma unroll
        for (int kt = 0; kt < 8; ++kt) {
            bf16x8 af = *(const bf16x8*)&Hlds[(wm * 16 + ln) * 264 + kt * 32 + quad * 8];
            #pragma unroll
            for (int nt = 0; nt < 8; ++nt) {
                int col = wn * 128 + nt * 16 + ln;
                bf16x8 bf = *(const bf16x8*)&W16[OFF_WD2 + (size_t)col * 256 + kt * 32 + quad * 8];
                acc[nt] = __builtin_amdgcn_mfma_f32_16x16x32_bf16(af, bf, acc[nt], 0, 0, 0);
            }
        }
        __syncthreads();   // Dlds reads done before Clds overwrite
        #pragma unroll
        for (int nt = 0; nt < 8; ++nt) {
            int col = wn * 128 + nt * 16 + ln;
            #pragma unroll
            for (int r = 0; r < 4; ++r) {
                int row = wm * 16 + quad * 4 + r;
                Clds[row * 264 + col] = f2bf(acc[nt][r]);
            }
        }
    }
    __syncthreads();

    // ---- P5: gate GEMM + delta ----
    {
        f32x4 acc[8];
        #pragma unroll
        for (int i = 0; i < 8; ++i) acc[i] = (f32x4){0.f, 0.f, 0.f, 0.f};
        #pragma unroll
        for (int kt = 0; kt < 8; ++kt) {
            bf16x8 af = *(const bf16x8*)&Clds[(wm * 16 + ln) * 264 + kt * 32 + quad * 8];
            #pragma unroll
            for (int nt = 0; nt < 8; ++nt) {
                int col = wn * 128 + nt * 16 + ln;
                bf16x8 bf = *(const bf16x8*)&W16[OFF_WG + (size_t)col * 256 + kt * 32 + quad * 8];
                acc[nt] = __builtin_amdgcn_mfma_f32_16x16x32_bf16(af, bf, acc[nt], 0, 0, 0);
            }
        }
        float trs = tanhf(rs[0]);
        #pragma unroll
        for (int nt = 0; nt < 8; ++nt) {
            int col = wn * 128 + nt * 16 + ln;
            float wgl = bf2f(W16[OFF_WGL + col]);
            #pragma unroll
            for (int r = 0; r < 4; ++r) {
                int row = wm * 16 + quad * 4 + r;
                float mrow = mask[m0 + row];
                float logit = acc[nt][r] + mrow * wgl;
                float gate = mrow / (1.0f + __expf(-logit));
                float corr = bf2f(Clds[row * 264 + col]);
                tileB[col * 40 + row] = f2bf(trs * gate * corr);
            }
        }
    }
    __syncthreads();

    // ---- store: out[b,ch,p] = x + delta ----
    #pragma unroll
    for (int i = 0; i < 4; ++i) {
        int idx = tid + i * 256;
        int ch = idx >> 2, p8 = (idx & 3) * 8;
        bf16x8 d = *(const bf16x8*)&tileB[ch * 40 + p8];
        size_t o = ((size_t)b * CC + ch) * NN + p0l + p8;
        float4 x0 = *(const float4*)&x[o];
        float4 x1 = *(const float4*)&x[o + 4];
        float4 o0, o1;
        o0.x = x0.x + bf2f(d[0]); o0.y = x0.y + bf2f(d[1]);
        o0.z = x0.z + bf2f(d[2]); o0.w = x0.w + bf2f(d[3]);
        o1.x = x1.x + bf2f(d[4]); o1.y = x1.y + bf2f(d[5]);
        o1.z = x1.z + bf2f(d[6]); o1.w = x1.w + bf2f(d[7]);
        *(float4*)&out[o] = o0;
        *(float4*)&out[o + 4] = o1;
    }
}

// ---------------------------------------------------------------------------
extern "C" void kernel_launch(void* const* d_in, const int* in_sizes, int n_in,
                              void* d_out, int out_size, void* d_ws, size_t ws_size,
                              hipStream_t stream) {
    const float* x     = (const float*)d_in[0];
    const float* mask  = (const float*)d_in[1];
    const float* gamma = (const float*)d_in[2];
    const float* beta  = (const float*)d_in[3];
    const float* wq    = (const float*)d_in[4];
    const float* wk    = (const float*)d_in[5];
    const float* wv    = (const float*)d_in[6];
    const float* w_out = (const float*)d_in[7];
    const float* w_qm  = (const float*)d_in[8];
    const float* wd1   = (const float*)d_in[9];
    const float* wd2   = (const float*)d_in[10];
    const float* wg    = (const float*)d_in[11];
    const float* rs    = (const float*)d_in[12];
    float* out = (float*)d_out;

    const size_t NC = (size_t)NTOT * CC;
    const size_t NE = (size_t)NTOT * EE;
    short* Xn16  = (short*)d_ws;        // NC
    short* Xt16  = Xn16 + NC;           // NC
    short* Q16   = Xt16 + NC;           // NE
    short* K16   = Q16 + NE;            // NE
    short* V16t  = K16 + NE;            // NC
    short* W16   = V16t + NC;           // W16_TOTAL
    short* Opart = W16 + W16_TOTAL;     // 4*NC
    float* Lpart = (float*)(Opart + 4 * NC);   // 4*NTOT f32
    // ~66 MB total

    ln_kernel<<<512, 256, 0, stream>>>(x, gamma, beta, wq, wk, wv, w_out,
                                       wd1, wd2, wg, W16, Xt16, Xn16);
    proj_kernel<<<1024, 256, 0, stream>>>(Xn16, Xt16, W16, mask, w_qm,
                                          Q16, K16, V16t);
    attn_kernel<<<1024, 256, 0, stream>>>(Q16, K16, V16t, mask, Opart, Lpart);
    epi_kernel<<<512, 256, 0, stream>>>(Opart, Lpart, W16, Xt16, Xn16, mask,
                                        rs, x, out);
}